// Round 11
// baseline (1004.732 us; speedup 1.0000x reference)
//
#include <hip/hip_runtime.h>
#include <stdint.h>

#define N_NODES 20000
#define E_EDGES 320000
#define H_DIM 128
#define A_DIM 512
#define NEMB_N 400
#define K_SEL 80000u
#define NBK 131072            /* 2^17 bins over key>>47 */
#define CAND_MAX 16384
#define SCAN_PER (NBK / 1024) /* 128 */

#define NODE_BLKS (N_NODES / 8)      /* 2500 */
#define DIST_BLKS (NEMB_N / 8)       /* 50   */

struct SelState {
    int b1; unsigned cum1; unsigned r1;
    int b2; unsigned cum2; unsigned r2;
    unsigned long long T;
};

// ---------------- threefry2x32 (JAX, 20 rounds) ----------------
__device__ __forceinline__ uint32_t rotl32(uint32_t x, int r) {
    return (x << r) | (x >> (32 - r));
}

__device__ __forceinline__ void threefry2x32(uint32_t k0, uint32_t k1,
                                             uint32_t& x0, uint32_t& x1) {
    uint32_t ks0 = k0, ks1 = k1, ks2 = k0 ^ k1 ^ 0x1BD11BDAu;
    x0 += ks0; x1 += ks1;
    x0 += x1; x1 = rotl32(x1, 13); x1 ^= x0;
    x0 += x1; x1 = rotl32(x1, 15); x1 ^= x0;
    x0 += x1; x1 = rotl32(x1, 26); x1 ^= x0;
    x0 += x1; x1 = rotl32(x1, 6);  x1 ^= x0;
    x0 += ks1; x1 += ks2 + 1u;
    x0 += x1; x1 = rotl32(x1, 17); x1 ^= x0;
    x0 += x1; x1 = rotl32(x1, 29); x1 ^= x0;
    x0 += x1; x1 = rotl32(x1, 16); x1 ^= x0;
    x0 += x1; x1 = rotl32(x1, 24); x1 ^= x0;
    x0 += ks2; x1 += ks0 + 2u;
    x0 += x1; x1 = rotl32(x1, 13); x1 ^= x0;
    x0 += x1; x1 = rotl32(x1, 15); x1 ^= x0;
    x0 += x1; x1 = rotl32(x1, 26); x1 ^= x0;
    x0 += x1; x1 = rotl32(x1, 6);  x1 ^= x0;
    x0 += ks0; x1 += ks1 + 3u;
    x0 += x1; x1 = rotl32(x1, 17); x1 ^= x0;
    x0 += x1; x1 = rotl32(x1, 29); x1 ^= x0;
    x0 += x1; x1 = rotl32(x1, 16); x1 ^= x0;
    x0 += x1; x1 = rotl32(x1, 24); x1 ^= x0;
    x0 += ks1; x1 += ks2 + 4u;
    x0 += x1; x1 = rotl32(x1, 13); x1 ^= x0;
    x0 += x1; x1 = rotl32(x1, 15); x1 ^= x0;
    x0 += x1; x1 = rotl32(x1, 26); x1 ^= x0;
    x0 += x1; x1 = rotl32(x1, 6);  x1 ^= x0;
    x0 += ks2; x1 += ks0 + 5u;
}

// ---------- fused node precompute + dist table (f32) ----------
// Blocks [0, NODE_BLKS): 8 nodes per block (measured-best shape).
// Blocks [NODE_BLKS, NODE_BLKS+DIST_BLKS): 8 dist rows each,
// dist_q = dist_table @ Wq[640:768] (verbatim former k_dist body).
__global__ __launch_bounds__(128) void k_node(
    const float* __restrict__ x, const float* __restrict__ aerial,
    const float* __restrict__ Wlin, const float* __restrict__ blin,
    const float* __restrict__ Wq, const float* __restrict__ bq,
    const float* __restrict__ Wv, const float* __restrict__ bv,
    const float* __restrict__ dtab,
    float* __restrict__ xl32, float* __restrict__ q32, float* __restrict__ v32,
    float* __restrict__ dq32) {
    __shared__ float xinT[H_DIM][8];   // [k][m]
    __shared__ float xsT[H_DIM][8];
    __shared__ float aerT[A_DIM][8];
    const int j = threadIdx.x;

    if (blockIdx.x >= NODE_BLKS) {
        // ---- dist path (verbatim former k_dist) ----
        const int n0 = (blockIdx.x - NODE_BLKS) * 8;
#pragma unroll
        for (int m = 0; m < 8; ++m) xinT[j][m] = dtab[(size_t)(n0 + m) * H_DIM + j];
        __syncthreads();
        float acc[8];
#pragma unroll
        for (int m = 0; m < 8; ++m) acc[m] = 0.0f;
        for (int k = 0; k < H_DIM; ++k) {
            float w = Wq[(size_t)(H_DIM + A_DIM + k) * H_DIM + j];
            const float4* xp = (const float4*)&xinT[k][0];
            float4 a0 = xp[0], a1 = xp[1];
            acc[0] = fmaf(a0.x, w, acc[0]); acc[1] = fmaf(a0.y, w, acc[1]);
            acc[2] = fmaf(a0.z, w, acc[2]); acc[3] = fmaf(a0.w, w, acc[3]);
            acc[4] = fmaf(a1.x, w, acc[4]); acc[5] = fmaf(a1.y, w, acc[5]);
            acc[6] = fmaf(a1.z, w, acc[6]); acc[7] = fmaf(a1.w, w, acc[7]);
        }
#pragma unroll
        for (int m = 0; m < 8; ++m) dq32[(size_t)(n0 + m) * H_DIM + j] = acc[m];
        return;
    }

    const int n0 = blockIdx.x * 8;
#pragma unroll
    for (int m = 0; m < 8; ++m) xinT[j][m] = x[(size_t)(n0 + m) * H_DIM + j];
#pragma unroll
    for (int m = 0; m < 8; ++m)
#pragma unroll
        for (int c = 0; c < 4; ++c)
            aerT[c * H_DIM + j][m] = aerial[(size_t)(n0 + m) * A_DIM + c * H_DIM + j];
    __syncthreads();
    // xl = x @ Wlin + blin
    float acc[8];
    {
        float bj = blin[j];
#pragma unroll
        for (int m = 0; m < 8; ++m) acc[m] = bj;
        for (int k = 0; k < H_DIM; ++k) {
            float w = Wlin[k * H_DIM + j];
            const float4* xp = (const float4*)&xinT[k][0];
            float4 a0 = xp[0], a1 = xp[1];
            acc[0] = fmaf(a0.x, w, acc[0]); acc[1] = fmaf(a0.y, w, acc[1]);
            acc[2] = fmaf(a0.z, w, acc[2]); acc[3] = fmaf(a0.w, w, acc[3]);
            acc[4] = fmaf(a1.x, w, acc[4]); acc[5] = fmaf(a1.y, w, acc[5]);
            acc[6] = fmaf(a1.z, w, acc[6]); acc[7] = fmaf(a1.w, w, acc[7]);
        }
    }
#pragma unroll
    for (int m = 0; m < 8; ++m) {
        xsT[j][m] = acc[m];
        xl32[(size_t)(n0 + m) * H_DIM + j] = acc[m];
    }
    __syncthreads();
    // v_node = xl @ Wv + bv
    {
        float bj = bv[j];
        float av[8];
#pragma unroll
        for (int m = 0; m < 8; ++m) av[m] = bj;
        for (int k = 0; k < H_DIM; ++k) {
            float w = Wv[k * H_DIM + j];
            const float4* xp = (const float4*)&xsT[k][0];
            float4 a0 = xp[0], a1 = xp[1];
            av[0] = fmaf(a0.x, w, av[0]); av[1] = fmaf(a0.y, w, av[1]);
            av[2] = fmaf(a0.z, w, av[2]); av[3] = fmaf(a0.w, w, av[3]);
            av[4] = fmaf(a1.x, w, av[4]); av[5] = fmaf(a1.y, w, av[5]);
            av[6] = fmaf(a1.z, w, av[6]); av[7] = fmaf(a1.w, w, av[7]);
        }
#pragma unroll
        for (int m = 0; m < 8; ++m) v32[(size_t)(n0 + m) * H_DIM + j] = av[m];
    }
    // q_node = xl @ Wq[0:128] + aerial @ Wq[128:640] + bq
    {
        float bj = bq[j];
        float aq[8];
#pragma unroll
        for (int m = 0; m < 8; ++m) aq[m] = bj;
        for (int k = 0; k < H_DIM; ++k) {
            float w = Wq[k * H_DIM + j];
            const float4* xp = (const float4*)&xsT[k][0];
            float4 a0 = xp[0], a1 = xp[1];
            aq[0] = fmaf(a0.x, w, aq[0]); aq[1] = fmaf(a0.y, w, aq[1]);
            aq[2] = fmaf(a0.z, w, aq[2]); aq[3] = fmaf(a0.w, w, aq[3]);
            aq[4] = fmaf(a1.x, w, aq[4]); aq[5] = fmaf(a1.y, w, aq[5]);
            aq[6] = fmaf(a1.z, w, aq[6]); aq[7] = fmaf(a1.w, w, aq[7]);
        }
        for (int k = 0; k < A_DIM; ++k) {
            float w = Wq[(size_t)(H_DIM + k) * H_DIM + j];
            const float4* xp = (const float4*)&aerT[k][0];
            float4 a0 = xp[0], a1 = xp[1];
            aq[0] = fmaf(a0.x, w, aq[0]); aq[1] = fmaf(a0.y, w, aq[1]);
            aq[2] = fmaf(a0.z, w, aq[2]); aq[3] = fmaf(a0.w, w, aq[3]);
            aq[4] = fmaf(a1.x, w, aq[4]); aq[5] = fmaf(a1.y, w, aq[5]);
            aq[6] = fmaf(a1.z, w, aq[6]); aq[7] = fmaf(a1.w, w, aq[7]);
        }
#pragma unroll
        for (int m = 0; m < 8; ++m) q32[(size_t)(n0 + m) * H_DIM + j] = aq[m];
    }
}

// ---------- per-edge score: 32-lane group handles 4 edges (measured best) ----------
// Histogram is taken directly on the TOP 17 BITS of the sort key
// (monotone in score) -> single-level selection; the former float-bin
// hist1/hist2 refine and the s32 array are gone. T is still the exact
// rank-K_SEL order statistic of the unique keys.
__global__ __launch_bounds__(256) void k_score(
    const int* __restrict__ ei, const int* __restrict__ dist,
    const float* __restrict__ q32, const float* __restrict__ v32,
    const float* __restrict__ dq32,
    unsigned long long* __restrict__ keys,
    unsigned* __restrict__ hist1) {
    const int g = threadIdx.x >> 5, lane = threadIdx.x & 31;
    const int e0 = blockIdx.x * 32 + g * 4;

    const int s0 = ei[e0 + 0], s1 = ei[e0 + 1], s2 = ei[e0 + 2], s3 = ei[e0 + 3];
    const int t0 = ei[E_EDGES + e0 + 0], t1 = ei[E_EDGES + e0 + 1];
    const int t2 = ei[E_EDGES + e0 + 2], t3 = ei[E_EDGES + e0 + 3];
    const int d0 = dist[e0 + 0] / 50, d1 = dist[e0 + 1] / 50;
    const int d2 = dist[e0 + 2] / 50, d3 = dist[e0 + 3] / 50;

    float4 q0 = ((const float4*)(q32 + (size_t)s0 * H_DIM))[lane];
    float4 q1 = ((const float4*)(q32 + (size_t)s1 * H_DIM))[lane];
    float4 q2 = ((const float4*)(q32 + (size_t)s2 * H_DIM))[lane];
    float4 q3 = ((const float4*)(q32 + (size_t)s3 * H_DIM))[lane];
    float4 v0 = ((const float4*)(v32 + (size_t)t0 * H_DIM))[lane];
    float4 v1 = ((const float4*)(v32 + (size_t)t1 * H_DIM))[lane];
    float4 v2 = ((const float4*)(v32 + (size_t)t2 * H_DIM))[lane];
    float4 v3 = ((const float4*)(v32 + (size_t)t3 * H_DIM))[lane];
    float4 w0 = ((const float4*)(dq32 + (size_t)d0 * H_DIM))[lane];
    float4 w1 = ((const float4*)(dq32 + (size_t)d1 * H_DIM))[lane];
    float4 w2 = ((const float4*)(dq32 + (size_t)d2 * H_DIM))[lane];
    float4 w3 = ((const float4*)(dq32 + (size_t)d3 * H_DIM))[lane];

    float ax, ay, az, aw;
    ax = q0.x + w0.x - v0.x; ay = q0.y + w0.y - v0.y;
    az = q0.z + w0.z - v0.z; aw = q0.w + w0.w - v0.w;
    float ss0 = fmaf(ax, ax, fmaf(ay, ay, fmaf(az, az, aw * aw)));
    ax = q1.x + w1.x - v1.x; ay = q1.y + w1.y - v1.y;
    az = q1.z + w1.z - v1.z; aw = q1.w + w1.w - v1.w;
    float ss1 = fmaf(ax, ax, fmaf(ay, ay, fmaf(az, az, aw * aw)));
    ax = q2.x + w2.x - v2.x; ay = q2.y + w2.y - v2.y;
    az = q2.z + w2.z - v2.z; aw = q2.w + w2.w - v2.w;
    float ss2 = fmaf(ax, ax, fmaf(ay, ay, fmaf(az, az, aw * aw)));
    ax = q3.x + w3.x - v3.x; ay = q3.y + w3.y - v3.y;
    az = q3.z + w3.z - v3.z; aw = q3.w + w3.w - v3.w;
    float ss3 = fmaf(ax, ax, fmaf(ay, ay, fmaf(az, az, aw * aw)));

#pragma unroll
    for (int o = 16; o > 0; o >>= 1) {
        ss0 += __shfl_xor(ss0, o, 64);
        ss1 += __shfl_xor(ss1, o, 64);
        ss2 += __shfl_xor(ss2, o, 64);
        ss3 += __shfl_xor(ss3, o, 64);
    }
    if (lane < 4) {
        float ssv = (lane == 0) ? ss0 : (lane == 1) ? ss1 : (lane == 2) ? ss2 : ss3;
        const int e = e0 + lane;
        // inline JAX threefry: counter=(0,e), key=(0,42), bits = out0^out1
        uint32_t x0r = 0u, x1r = (uint32_t)e;
        threefry2x32(0u, 42u, x0r, x1r);
        uint32_t bits = x0r ^ x1r;
        float uu = __uint_as_float((bits >> 9) | 0x3f800000u) - 1.0f;
        float nrm = sqrtf(ssv);
        float a = -logf(uu + 1e-20f);
        float gm = -logf(a + 1e-20f);
        float score = gm - nrm;
        int ib = __float_as_int(score);
        unsigned m32 = (ib < 0) ? ~(unsigned)ib : ((unsigned)ib | 0x80000000u);
        // unique key: score-ordered high bits, lower edge index wins ties
        unsigned long long key =
            ((unsigned long long)m32 << 32) | (unsigned)(0xFFFFFFFFu - (unsigned)e);
        keys[e] = key;
        atomicAdd(&hist1[(unsigned)(key >> 47)], 1u);
    }
}

// descending scan over 131072 key-bins to locate the bin holding rank K_SEL
__global__ __launch_bounds__(1024) void k_scan(const unsigned* __restrict__ hist,
                                               SelState* st) {
    __shared__ unsigned csum[1024];
    __shared__ unsigned bins[SCAN_PER];
    __shared__ int selc;
    __shared__ unsigned cumbase;
    const int t = threadIdx.x;
    unsigned s = 0;
    for (int i = 0; i < SCAN_PER; ++i) s += hist[t * SCAN_PER + i];
    csum[t] = s;
    __syncthreads();
    if (t == 0) {
        unsigned cum = 0; int c = 1023;
        for (; c >= 0; --c) {
            if (cum + csum[c] >= K_SEL) break;
            cum += csum[c];
        }
        selc = c; cumbase = cum;
    }
    __syncthreads();
    if (t < SCAN_PER) bins[t] = hist[selc * SCAN_PER + t];
    __syncthreads();
    if (t == 0) {
        unsigned cum = cumbase; int b = -1;
        for (int i = SCAN_PER - 1; i >= 0; --i) {
            if (cum + bins[i] >= K_SEL) { b = selc * SCAN_PER + i; break; }
            cum += bins[i];
        }
        st->b1 = b; st->cum1 = cum; st->r1 = K_SEL - cum;
    }
}

__global__ __launch_bounds__(256) void k_collect(
    const unsigned long long* __restrict__ keys,
    const SelState* __restrict__ st, unsigned long long* __restrict__ cand,
    unsigned* __restrict__ cnt) {
    int e = blockIdx.x * 256 + threadIdx.x;
    if (e >= E_EDGES) return;
    unsigned long long k = keys[e];
    if ((int)(unsigned)(k >> 47) != st->b1) return;
    unsigned p = atomicAdd(cnt, 1u);
    if (p < CAND_MAX) cand[p] = k;
}

// T = r1-th largest key among candidates (keys are unique); 1024 threads
// since the single-level bin holds O(1e3) candidates
__global__ __launch_bounds__(1024) void k_thresh(
    const unsigned long long* __restrict__ cand, const unsigned* __restrict__ cnt,
    SelState* st) {
    int c = (int)min(*cnt, (unsigned)CAND_MAX);
    unsigned r = st->r1;
    for (int i = threadIdx.x; i < c; i += 1024) {
        unsigned long long ki = cand[i];
        unsigned g = 0;
        for (int j = 0; j < c; ++j) g += (cand[j] > ki);
        if (g == r - 1) st->T = ki;
    }
}

// wave per edge: key >= T selects; scatter xl[src] into msg[tgt] + deg
__global__ __launch_bounds__(256) void k_scatter(
    const int* __restrict__ ei, const unsigned long long* __restrict__ keys,
    const SelState* __restrict__ st, const float* __restrict__ xl32,
    float* __restrict__ msg, float* __restrict__ deg) {
    const int wid = threadIdx.x >> 6, lane = threadIdx.x & 63;
    const int e = blockIdx.x * 4 + wid;
    if (keys[e] >= st->T) {
        int sidx = ei[e], tidx = ei[E_EDGES + e];
        const float* xp = xl32 + (size_t)sidx * H_DIM;
        float* mp = msg + (size_t)tidx * H_DIM;
        const int h = lane * 2;
        atomicAdd(&mp[h], xp[h]);
        atomicAdd(&mp[h + 1], xp[h + 1]);
        if (lane == 0) atomicAdd(&deg[tidx], 1.0f);
    }
}

// out = (msg/max(deg,1)) @ Wl + bl + xl @ Wr
__global__ __launch_bounds__(128) void k_out(
    const float* __restrict__ msg, const float* __restrict__ deg,
    const float* __restrict__ xl32, const float* __restrict__ Wl,
    const float* __restrict__ bl, const float* __restrict__ Wr,
    float* __restrict__ out) {
    __shared__ float axT[H_DIM][8];
    __shared__ float xxT[H_DIM][8];
    const int j = threadIdx.x;
    const int n0 = blockIdx.x * 8;
#pragma unroll
    for (int m = 0; m < 8; ++m) {
        float d = fmaxf(deg[n0 + m], 1.0f);
        axT[j][m] = msg[(size_t)(n0 + m) * H_DIM + j] / d;
        xxT[j][m] = xl32[(size_t)(n0 + m) * H_DIM + j];
    }
    __syncthreads();
    float acc[8];
    float bj = bl[j];
#pragma unroll
    for (int m = 0; m < 8; ++m) acc[m] = bj;
    for (int k = 0; k < H_DIM; ++k) {
        float wl = Wl[k * H_DIM + j];
        float wr = Wr[k * H_DIM + j];
        const float4* ap = (const float4*)&axT[k][0];
        const float4* xp = (const float4*)&xxT[k][0];
        float4 a0 = ap[0], a1 = ap[1];
        float4 x0 = xp[0], x1 = xp[1];
        acc[0] = fmaf(a0.x, wl, fmaf(x0.x, wr, acc[0]));
        acc[1] = fmaf(a0.y, wl, fmaf(x0.y, wr, acc[1]));
        acc[2] = fmaf(a0.z, wl, fmaf(x0.z, wr, acc[2]));
        acc[3] = fmaf(a0.w, wl, fmaf(x0.w, wr, acc[3]));
        acc[4] = fmaf(a1.x, wl, fmaf(x1.x, wr, acc[4]));
        acc[5] = fmaf(a1.y, wl, fmaf(x1.y, wr, acc[5]));
        acc[6] = fmaf(a1.z, wl, fmaf(x1.z, wr, acc[6]));
        acc[7] = fmaf(a1.w, wl, fmaf(x1.w, wr, acc[7]));
    }
#pragma unroll
    for (int m = 0; m < 8; ++m) out[(size_t)(n0 + m) * H_DIM + j] = acc[m];
}

extern "C" void kernel_launch(void* const* d_in, const int* in_sizes, int n_in,
                              void* d_out, int out_size, void* d_ws, size_t ws_size,
                              hipStream_t stream) {
    const float* x      = (const float*)d_in[0];
    const int*   ei     = (const int*)d_in[1];
    const int*   dist   = (const int*)d_in[2];
    const float* aerial = (const float*)d_in[3];
    const float* Wlin   = (const float*)d_in[4];
    const float* blin   = (const float*)d_in[5];
    const float* Wq     = (const float*)d_in[6];
    const float* bq     = (const float*)d_in[7];
    const float* Wv     = (const float*)d_in[8];
    const float* bv     = (const float*)d_in[9];
    const float* dtab   = (const float*)d_in[10];
    const float* Wl     = (const float*)d_in[11];
    const float* bl     = (const float*)d_in[12];
    const float* Wr     = (const float*)d_in[13];
    float* out = (float*)d_out;

    char* ws = (char*)d_ws;
    size_t off = 0;
    auto alloc = [&](size_t bytes) -> void* {
        void* p = ws + off;
        off += (bytes + 255) & ~(size_t)255;
        return p;
    };
    float* q32  = (float*)alloc((size_t)N_NODES * H_DIM * 4);
    float* v32  = (float*)alloc((size_t)N_NODES * H_DIM * 4);
    float* dq32 = (float*)alloc((size_t)NEMB_N * H_DIM * 4);
    unsigned long long* keys = (unsigned long long*)alloc((size_t)E_EDGES * 8);
    float* xl32 = (float*)alloc((size_t)N_NODES * H_DIM * 4);
    char* zbase = ws + off;
    float* msg  = (float*)alloc((size_t)N_NODES * H_DIM * 4);
    float* deg  = (float*)alloc((size_t)N_NODES * 4);
    unsigned* hist1 = (unsigned*)alloc((size_t)NBK * 4);
    unsigned long long* cand = (unsigned long long*)alloc((size_t)CAND_MAX * 8);
    unsigned* counters = (unsigned*)alloc(256);   // [0]=candCount
    SelState* st = (SelState*)alloc(256);
    size_t zlen = (size_t)((ws + off) - zbase);

    hipMemsetAsync(zbase, 0, zlen, stream);

    k_node<<<NODE_BLKS + DIST_BLKS, 128, 0, stream>>>(
        x, aerial, Wlin, blin, Wq, bq, Wv, bv, dtab, xl32, q32, v32, dq32);
    k_score<<<E_EDGES / 32, 256, 0, stream>>>(ei, dist, q32, v32, dq32,
                                              keys, hist1);
    k_scan<<<1, 1024, 0, stream>>>(hist1, st);
    k_collect<<<(E_EDGES + 255) / 256, 256, 0, stream>>>(keys, st, cand, &counters[0]);
    k_thresh<<<1, 1024, 0, stream>>>(cand, &counters[0], st);
    k_scatter<<<E_EDGES / 4, 256, 0, stream>>>(ei, keys, st, xl32, msg, deg);
    k_out<<<N_NODES / 8, 128, 0, stream>>>(msg, deg, xl32, Wl, bl, Wr, out);
}

// Round 12
// 646.958 us; speedup vs baseline: 1.5530x; 1.5530x over previous
//
#include <hip/hip_runtime.h>
#include <stdint.h>

#define N_NODES 20000
#define E_EDGES 320000
#define H_DIM 128
#define A_DIM 512
#define NEMB_N 400
#define K_SEL 80000u
#define NBK (1u << 20)        /* 2^20 bins over key>>44 (11 mantissa bits) */
#define CAND_MAX 16384
#define SCAN_PER 1024         /* NBK / 1024 threads */

#define NODE_BLKS (N_NODES / 8)      /* 2500 */
#define DIST_BLKS (NEMB_N / 8)       /* 50   */

struct SelState {
    int b1; unsigned cum1; unsigned r1;
    int b2; unsigned cum2; unsigned r2;
    unsigned long long T;
};

// ---------------- threefry2x32 (JAX, 20 rounds) ----------------
__device__ __forceinline__ uint32_t rotl32(uint32_t x, int r) {
    return (x << r) | (x >> (32 - r));
}

__device__ __forceinline__ void threefry2x32(uint32_t k0, uint32_t k1,
                                             uint32_t& x0, uint32_t& x1) {
    uint32_t ks0 = k0, ks1 = k1, ks2 = k0 ^ k1 ^ 0x1BD11BDAu;
    x0 += ks0; x1 += ks1;
    x0 += x1; x1 = rotl32(x1, 13); x1 ^= x0;
    x0 += x1; x1 = rotl32(x1, 15); x1 ^= x0;
    x0 += x1; x1 = rotl32(x1, 26); x1 ^= x0;
    x0 += x1; x1 = rotl32(x1, 6);  x1 ^= x0;
    x0 += ks1; x1 += ks2 + 1u;
    x0 += x1; x1 = rotl32(x1, 17); x1 ^= x0;
    x0 += x1; x1 = rotl32(x1, 29); x1 ^= x0;
    x0 += x1; x1 = rotl32(x1, 16); x1 ^= x0;
    x0 += x1; x1 = rotl32(x1, 24); x1 ^= x0;
    x0 += ks2; x1 += ks0 + 2u;
    x0 += x1; x1 = rotl32(x1, 13); x1 ^= x0;
    x0 += x1; x1 = rotl32(x1, 15); x1 ^= x0;
    x0 += x1; x1 = rotl32(x1, 26); x1 ^= x0;
    x0 += x1; x1 = rotl32(x1, 6);  x1 ^= x0;
    x0 += ks0; x1 += ks1 + 3u;
    x0 += x1; x1 = rotl32(x1, 17); x1 ^= x0;
    x0 += x1; x1 = rotl32(x1, 29); x1 ^= x0;
    x0 += x1; x1 = rotl32(x1, 16); x1 ^= x0;
    x0 += x1; x1 = rotl32(x1, 24); x1 ^= x0;
    x0 += ks1; x1 += ks2 + 4u;
    x0 += x1; x1 = rotl32(x1, 13); x1 ^= x0;
    x0 += x1; x1 = rotl32(x1, 15); x1 ^= x0;
    x0 += x1; x1 = rotl32(x1, 26); x1 ^= x0;
    x0 += x1; x1 = rotl32(x1, 6);  x1 ^= x0;
    x0 += ks2; x1 += ks0 + 5u;
}

// ---------- fused node precompute + dist table (f32) ----------
// Blocks [0, NODE_BLKS): 8 nodes per block (measured-best shape).
// Blocks [NODE_BLKS, NODE_BLKS+DIST_BLKS): 8 dist rows each,
// dist_q = dist_table @ Wq[640:768] (verbatim former k_dist body).
__global__ __launch_bounds__(128) void k_node(
    const float* __restrict__ x, const float* __restrict__ aerial,
    const float* __restrict__ Wlin, const float* __restrict__ blin,
    const float* __restrict__ Wq, const float* __restrict__ bq,
    const float* __restrict__ Wv, const float* __restrict__ bv,
    const float* __restrict__ dtab,
    float* __restrict__ xl32, float* __restrict__ q32, float* __restrict__ v32,
    float* __restrict__ dq32) {
    __shared__ float xinT[H_DIM][8];   // [k][m]
    __shared__ float xsT[H_DIM][8];
    __shared__ float aerT[A_DIM][8];
    const int j = threadIdx.x;

    if (blockIdx.x >= NODE_BLKS) {
        // ---- dist path (verbatim former k_dist) ----
        const int n0 = (blockIdx.x - NODE_BLKS) * 8;
#pragma unroll
        for (int m = 0; m < 8; ++m) xinT[j][m] = dtab[(size_t)(n0 + m) * H_DIM + j];
        __syncthreads();
        float acc[8];
#pragma unroll
        for (int m = 0; m < 8; ++m) acc[m] = 0.0f;
        for (int k = 0; k < H_DIM; ++k) {
            float w = Wq[(size_t)(H_DIM + A_DIM + k) * H_DIM + j];
            const float4* xp = (const float4*)&xinT[k][0];
            float4 a0 = xp[0], a1 = xp[1];
            acc[0] = fmaf(a0.x, w, acc[0]); acc[1] = fmaf(a0.y, w, acc[1]);
            acc[2] = fmaf(a0.z, w, acc[2]); acc[3] = fmaf(a0.w, w, acc[3]);
            acc[4] = fmaf(a1.x, w, acc[4]); acc[5] = fmaf(a1.y, w, acc[5]);
            acc[6] = fmaf(a1.z, w, acc[6]); acc[7] = fmaf(a1.w, w, acc[7]);
        }
#pragma unroll
        for (int m = 0; m < 8; ++m) dq32[(size_t)(n0 + m) * H_DIM + j] = acc[m];
        return;
    }

    const int n0 = blockIdx.x * 8;
#pragma unroll
    for (int m = 0; m < 8; ++m) xinT[j][m] = x[(size_t)(n0 + m) * H_DIM + j];
#pragma unroll
    for (int m = 0; m < 8; ++m)
#pragma unroll
        for (int c = 0; c < 4; ++c)
            aerT[c * H_DIM + j][m] = aerial[(size_t)(n0 + m) * A_DIM + c * H_DIM + j];
    __syncthreads();
    // xl = x @ Wlin + blin
    float acc[8];
    {
        float bj = blin[j];
#pragma unroll
        for (int m = 0; m < 8; ++m) acc[m] = bj;
        for (int k = 0; k < H_DIM; ++k) {
            float w = Wlin[k * H_DIM + j];
            const float4* xp = (const float4*)&xinT[k][0];
            float4 a0 = xp[0], a1 = xp[1];
            acc[0] = fmaf(a0.x, w, acc[0]); acc[1] = fmaf(a0.y, w, acc[1]);
            acc[2] = fmaf(a0.z, w, acc[2]); acc[3] = fmaf(a0.w, w, acc[3]);
            acc[4] = fmaf(a1.x, w, acc[4]); acc[5] = fmaf(a1.y, w, acc[5]);
            acc[6] = fmaf(a1.z, w, acc[6]); acc[7] = fmaf(a1.w, w, acc[7]);
        }
    }
#pragma unroll
    for (int m = 0; m < 8; ++m) {
        xsT[j][m] = acc[m];
        xl32[(size_t)(n0 + m) * H_DIM + j] = acc[m];
    }
    __syncthreads();
    // v_node = xl @ Wv + bv
    {
        float bj = bv[j];
        float av[8];
#pragma unroll
        for (int m = 0; m < 8; ++m) av[m] = bj;
        for (int k = 0; k < H_DIM; ++k) {
            float w = Wv[k * H_DIM + j];
            const float4* xp = (const float4*)&xsT[k][0];
            float4 a0 = xp[0], a1 = xp[1];
            av[0] = fmaf(a0.x, w, av[0]); av[1] = fmaf(a0.y, w, av[1]);
            av[2] = fmaf(a0.z, w, av[2]); av[3] = fmaf(a0.w, w, av[3]);
            av[4] = fmaf(a1.x, w, av[4]); av[5] = fmaf(a1.y, w, av[5]);
            av[6] = fmaf(a1.z, w, av[6]); av[7] = fmaf(a1.w, w, av[7]);
        }
#pragma unroll
        for (int m = 0; m < 8; ++m) v32[(size_t)(n0 + m) * H_DIM + j] = av[m];
    }
    // q_node = xl @ Wq[0:128] + aerial @ Wq[128:640] + bq
    {
        float bj = bq[j];
        float aq[8];
#pragma unroll
        for (int m = 0; m < 8; ++m) aq[m] = bj;
        for (int k = 0; k < H_DIM; ++k) {
            float w = Wq[k * H_DIM + j];
            const float4* xp = (const float4*)&xsT[k][0];
            float4 a0 = xp[0], a1 = xp[1];
            aq[0] = fmaf(a0.x, w, aq[0]); aq[1] = fmaf(a0.y, w, aq[1]);
            aq[2] = fmaf(a0.z, w, aq[2]); aq[3] = fmaf(a0.w, w, aq[3]);
            aq[4] = fmaf(a1.x, w, aq[4]); aq[5] = fmaf(a1.y, w, aq[5]);
            aq[6] = fmaf(a1.z, w, aq[6]); aq[7] = fmaf(a1.w, w, aq[7]);
        }
        for (int k = 0; k < A_DIM; ++k) {
            float w = Wq[(size_t)(H_DIM + k) * H_DIM + j];
            const float4* xp = (const float4*)&aerT[k][0];
            float4 a0 = xp[0], a1 = xp[1];
            aq[0] = fmaf(a0.x, w, aq[0]); aq[1] = fmaf(a0.y, w, aq[1]);
            aq[2] = fmaf(a0.z, w, aq[2]); aq[3] = fmaf(a0.w, w, aq[3]);
            aq[4] = fmaf(a1.x, w, aq[4]); aq[5] = fmaf(a1.y, w, aq[5]);
            aq[6] = fmaf(a1.z, w, aq[6]); aq[7] = fmaf(a1.w, w, aq[7]);
        }
#pragma unroll
        for (int m = 0; m < 8; ++m) q32[(size_t)(n0 + m) * H_DIM + j] = aq[m];
    }
}

// ---------- per-edge score: 32-lane group handles 4 edges (measured best) ----------
// Histogram on the TOP 20 BITS of the monotone sort key (key>>44):
// 11 mantissa bits -> >=128 bins/unit score in the populated octave,
// finer than the old two-level hist1 (102/unit) -> no hot-bin atomic
// serialization (R11's key>>47 had only 8 mantissa bits -> ~16-32
// bins/unit -> one bin absorbed ~1e5 atomics -> +260us stall).
// T is still the exact rank-K_SEL order statistic of the unique keys.
__global__ __launch_bounds__(256) void k_score(
    const int* __restrict__ ei, const int* __restrict__ dist,
    const float* __restrict__ q32, const float* __restrict__ v32,
    const float* __restrict__ dq32,
    unsigned long long* __restrict__ keys,
    unsigned* __restrict__ hist1) {
    const int g = threadIdx.x >> 5, lane = threadIdx.x & 31;
    const int e0 = blockIdx.x * 32 + g * 4;

    const int s0 = ei[e0 + 0], s1 = ei[e0 + 1], s2 = ei[e0 + 2], s3 = ei[e0 + 3];
    const int t0 = ei[E_EDGES + e0 + 0], t1 = ei[E_EDGES + e0 + 1];
    const int t2 = ei[E_EDGES + e0 + 2], t3 = ei[E_EDGES + e0 + 3];
    const int d0 = dist[e0 + 0] / 50, d1 = dist[e0 + 1] / 50;
    const int d2 = dist[e0 + 2] / 50, d3 = dist[e0 + 3] / 50;

    float4 q0 = ((const float4*)(q32 + (size_t)s0 * H_DIM))[lane];
    float4 q1 = ((const float4*)(q32 + (size_t)s1 * H_DIM))[lane];
    float4 q2 = ((const float4*)(q32 + (size_t)s2 * H_DIM))[lane];
    float4 q3 = ((const float4*)(q32 + (size_t)s3 * H_DIM))[lane];
    float4 v0 = ((const float4*)(v32 + (size_t)t0 * H_DIM))[lane];
    float4 v1 = ((const float4*)(v32 + (size_t)t1 * H_DIM))[lane];
    float4 v2 = ((const float4*)(v32 + (size_t)t2 * H_DIM))[lane];
    float4 v3 = ((const float4*)(v32 + (size_t)t3 * H_DIM))[lane];
    float4 w0 = ((const float4*)(dq32 + (size_t)d0 * H_DIM))[lane];
    float4 w1 = ((const float4*)(dq32 + (size_t)d1 * H_DIM))[lane];
    float4 w2 = ((const float4*)(dq32 + (size_t)d2 * H_DIM))[lane];
    float4 w3 = ((const float4*)(dq32 + (size_t)d3 * H_DIM))[lane];

    float ax, ay, az, aw;
    ax = q0.x + w0.x - v0.x; ay = q0.y + w0.y - v0.y;
    az = q0.z + w0.z - v0.z; aw = q0.w + w0.w - v0.w;
    float ss0 = fmaf(ax, ax, fmaf(ay, ay, fmaf(az, az, aw * aw)));
    ax = q1.x + w1.x - v1.x; ay = q1.y + w1.y - v1.y;
    az = q1.z + w1.z - v1.z; aw = q1.w + w1.w - v1.w;
    float ss1 = fmaf(ax, ax, fmaf(ay, ay, fmaf(az, az, aw * aw)));
    ax = q2.x + w2.x - v2.x; ay = q2.y + w2.y - v2.y;
    az = q2.z + w2.z - v2.z; aw = q2.w + w2.w - v2.w;
    float ss2 = fmaf(ax, ax, fmaf(ay, ay, fmaf(az, az, aw * aw)));
    ax = q3.x + w3.x - v3.x; ay = q3.y + w3.y - v3.y;
    az = q3.z + w3.z - v3.z; aw = q3.w + w3.w - v3.w;
    float ss3 = fmaf(ax, ax, fmaf(ay, ay, fmaf(az, az, aw * aw)));

#pragma unroll
    for (int o = 16; o > 0; o >>= 1) {
        ss0 += __shfl_xor(ss0, o, 64);
        ss1 += __shfl_xor(ss1, o, 64);
        ss2 += __shfl_xor(ss2, o, 64);
        ss3 += __shfl_xor(ss3, o, 64);
    }
    if (lane < 4) {
        float ssv = (lane == 0) ? ss0 : (lane == 1) ? ss1 : (lane == 2) ? ss2 : ss3;
        const int e = e0 + lane;
        // inline JAX threefry: counter=(0,e), key=(0,42), bits = out0^out1
        uint32_t x0r = 0u, x1r = (uint32_t)e;
        threefry2x32(0u, 42u, x0r, x1r);
        uint32_t bits = x0r ^ x1r;
        float uu = __uint_as_float((bits >> 9) | 0x3f800000u) - 1.0f;
        float nrm = sqrtf(ssv);
        float a = -logf(uu + 1e-20f);
        float gm = -logf(a + 1e-20f);
        float score = gm - nrm;
        int ib = __float_as_int(score);
        unsigned m32 = (ib < 0) ? ~(unsigned)ib : ((unsigned)ib | 0x80000000u);
        // unique key: score-ordered high bits, lower edge index wins ties
        unsigned long long key =
            ((unsigned long long)m32 << 32) | (unsigned)(0xFFFFFFFFu - (unsigned)e);
        keys[e] = key;
        atomicAdd(&hist1[(unsigned)(key >> 44)], 1u);
    }
}

// descending scan over 2^20 key-bins to locate the bin holding rank K_SEL
__global__ __launch_bounds__(1024) void k_scan(const unsigned* __restrict__ hist,
                                               SelState* st) {
    __shared__ unsigned csum[1024];
    __shared__ unsigned binv[SCAN_PER];
    __shared__ int selc;
    __shared__ unsigned cumbase;
    const int t = threadIdx.x;
    unsigned s = 0;
    for (int i = 0; i < SCAN_PER; ++i) s += hist[(size_t)t * SCAN_PER + i];
    csum[t] = s;
    __syncthreads();
    if (t == 0) {
        unsigned cum = 0; int c = 1023;
        for (; c >= 0; --c) {
            if (cum + csum[c] >= K_SEL) break;
            cum += csum[c];
        }
        selc = c; cumbase = cum;
    }
    __syncthreads();
    binv[t] = hist[(size_t)selc * SCAN_PER + t];
    __syncthreads();
    if (t == 0) {
        unsigned cum = cumbase; int b = -1;
        for (int i = SCAN_PER - 1; i >= 0; --i) {
            if (cum + binv[i] >= K_SEL) { b = selc * SCAN_PER + i; break; }
            cum += binv[i];
        }
        st->b1 = b; st->cum1 = cum; st->r1 = K_SEL - cum;
    }
}

__global__ __launch_bounds__(256) void k_collect(
    const unsigned long long* __restrict__ keys,
    const SelState* __restrict__ st, unsigned long long* __restrict__ cand,
    unsigned* __restrict__ cnt) {
    int e = blockIdx.x * 256 + threadIdx.x;
    if (e >= E_EDGES) return;
    unsigned long long k = keys[e];
    if ((int)(unsigned)(k >> 44) != st->b1) return;
    unsigned p = atomicAdd(cnt, 1u);
    if (p < CAND_MAX) cand[p] = k;
}

// T = r1-th largest key among candidates (keys are unique)
__global__ __launch_bounds__(1024) void k_thresh(
    const unsigned long long* __restrict__ cand, const unsigned* __restrict__ cnt,
    SelState* st) {
    int c = (int)min(*cnt, (unsigned)CAND_MAX);
    unsigned r = st->r1;
    for (int i = threadIdx.x; i < c; i += 1024) {
        unsigned long long ki = cand[i];
        unsigned g = 0;
        for (int j = 0; j < c; ++j) g += (cand[j] > ki);
        if (g == r - 1) st->T = ki;
    }
}

// wave per edge: key >= T selects; scatter xl[src] into msg[tgt] + deg
__global__ __launch_bounds__(256) void k_scatter(
    const int* __restrict__ ei, const unsigned long long* __restrict__ keys,
    const SelState* __restrict__ st, const float* __restrict__ xl32,
    float* __restrict__ msg, float* __restrict__ deg) {
    const int wid = threadIdx.x >> 6, lane = threadIdx.x & 63;
    const int e = blockIdx.x * 4 + wid;
    if (keys[e] >= st->T) {
        int sidx = ei[e], tidx = ei[E_EDGES + e];
        const float* xp = xl32 + (size_t)sidx * H_DIM;
        float* mp = msg + (size_t)tidx * H_DIM;
        const int h = lane * 2;
        atomicAdd(&mp[h], xp[h]);
        atomicAdd(&mp[h + 1], xp[h + 1]);
        if (lane == 0) atomicAdd(&deg[tidx], 1.0f);
    }
}

// out = (msg/max(deg,1)) @ Wl + bl + xl @ Wr
__global__ __launch_bounds__(128) void k_out(
    const float* __restrict__ msg, const float* __restrict__ deg,
    const float* __restrict__ xl32, const float* __restrict__ Wl,
    const float* __restrict__ bl, const float* __restrict__ Wr,
    float* __restrict__ out) {
    __shared__ float axT[H_DIM][8];
    __shared__ float xxT[H_DIM][8];
    const int j = threadIdx.x;
    const int n0 = blockIdx.x * 8;
#pragma unroll
    for (int m = 0; m < 8; ++m) {
        float d = fmaxf(deg[n0 + m], 1.0f);
        axT[j][m] = msg[(size_t)(n0 + m) * H_DIM + j] / d;
        xxT[j][m] = xl32[(size_t)(n0 + m) * H_DIM + j];
    }
    __syncthreads();
    float acc[8];
    float bj = bl[j];
#pragma unroll
    for (int m = 0; m < 8; ++m) acc[m] = bj;
    for (int k = 0; k < H_DIM; ++k) {
        float wl = Wl[k * H_DIM + j];
        float wr = Wr[k * H_DIM + j];
        const float4* ap = (const float4*)&axT[k][0];
        const float4* xp = (const float4*)&xxT[k][0];
        float4 a0 = ap[0], a1 = ap[1];
        float4 x0 = xp[0], x1 = xp[1];
        acc[0] = fmaf(a0.x, wl, fmaf(x0.x, wr, acc[0]));
        acc[1] = fmaf(a0.y, wl, fmaf(x0.y, wr, acc[1]));
        acc[2] = fmaf(a0.z, wl, fmaf(x0.z, wr, acc[2]));
        acc[3] = fmaf(a0.w, wl, fmaf(x0.w, wr, acc[3]));
        acc[4] = fmaf(a1.x, wl, fmaf(x1.x, wr, acc[4]));
        acc[5] = fmaf(a1.y, wl, fmaf(x1.y, wr, acc[5]));
        acc[6] = fmaf(a1.z, wl, fmaf(x1.z, wr, acc[6]));
        acc[7] = fmaf(a1.w, wl, fmaf(x1.w, wr, acc[7]));
    }
#pragma unroll
    for (int m = 0; m < 8; ++m) out[(size_t)(n0 + m) * H_DIM + j] = acc[m];
}

extern "C" void kernel_launch(void* const* d_in, const int* in_sizes, int n_in,
                              void* d_out, int out_size, void* d_ws, size_t ws_size,
                              hipStream_t stream) {
    const float* x      = (const float*)d_in[0];
    const int*   ei     = (const int*)d_in[1];
    const int*   dist   = (const int*)d_in[2];
    const float* aerial = (const float*)d_in[3];
    const float* Wlin   = (const float*)d_in[4];
    const float* blin   = (const float*)d_in[5];
    const float* Wq     = (const float*)d_in[6];
    const float* bq     = (const float*)d_in[7];
    const float* Wv     = (const float*)d_in[8];
    const float* bv     = (const float*)d_in[9];
    const float* dtab   = (const float*)d_in[10];
    const float* Wl     = (const float*)d_in[11];
    const float* bl     = (const float*)d_in[12];
    const float* Wr     = (const float*)d_in[13];
    float* out = (float*)d_out;

    char* ws = (char*)d_ws;
    size_t off = 0;
    auto alloc = [&](size_t bytes) -> void* {
        void* p = ws + off;
        off += (bytes + 255) & ~(size_t)255;
        return p;
    };
    float* q32  = (float*)alloc((size_t)N_NODES * H_DIM * 4);
    float* v32  = (float*)alloc((size_t)N_NODES * H_DIM * 4);
    float* dq32 = (float*)alloc((size_t)NEMB_N * H_DIM * 4);
    unsigned long long* keys = (unsigned long long*)alloc((size_t)E_EDGES * 8);
    float* xl32 = (float*)alloc((size_t)N_NODES * H_DIM * 4);
    char* zbase = ws + off;
    float* msg  = (float*)alloc((size_t)N_NODES * H_DIM * 4);
    float* deg  = (float*)alloc((size_t)N_NODES * 4);
    unsigned* hist1 = (unsigned*)alloc((size_t)NBK * 4);
    unsigned long long* cand = (unsigned long long*)alloc((size_t)CAND_MAX * 8);
    unsigned* counters = (unsigned*)alloc(256);   // [0]=candCount
    SelState* st = (SelState*)alloc(256);
    size_t zlen = (size_t)((ws + off) - zbase);

    hipMemsetAsync(zbase, 0, zlen, stream);

    k_node<<<NODE_BLKS + DIST_BLKS, 128, 0, stream>>>(
        x, aerial, Wlin, blin, Wq, bq, Wv, bv, dtab, xl32, q32, v32, dq32);
    k_score<<<E_EDGES / 32, 256, 0, stream>>>(ei, dist, q32, v32, dq32,
                                              keys, hist1);
    k_scan<<<1, 1024, 0, stream>>>(hist1, st);
    k_collect<<<(E_EDGES + 255) / 256, 256, 0, stream>>>(keys, st, cand, &counters[0]);
    k_thresh<<<1, 1024, 0, stream>>>(cand, &counters[0], st);
    k_scatter<<<E_EDGES / 4, 256, 0, stream>>>(ei, keys, st, xl32, msg, deg);
    k_out<<<N_NODES / 8, 128, 0, stream>>>(msg, deg, xl32, Wl, bl, Wr, out);
}

// Round 13
// 535.994 us; speedup vs baseline: 1.8745x; 1.2070x over previous
//
#include <hip/hip_runtime.h>
#include <stdint.h>

#define N_NODES 20000
#define E_EDGES 320000
#define H_DIM 128
#define A_DIM 512
#define NEMB_N 400
#define K_SEL 80000u
#define NBK (1u << 20)        /* 2^20 bins over key>>44 (11 mantissa bits) */
#define CAND_MAX 16384
#define SCAN_PER 1024         /* bins per coarse chunk */
#define NCOARSE (NBK / SCAN_PER)   /* 1024 */

#define NODE_BLKS (N_NODES / 8)      /* 2500 */
#define DIST_BLKS (NEMB_N / 8)       /* 50   */

struct SelState {
    int b1; unsigned cum1; unsigned r1;
    int b2; unsigned cum2; unsigned r2;
    unsigned long long T;
};

// ---------------- threefry2x32 (JAX, 20 rounds) ----------------
__device__ __forceinline__ uint32_t rotl32(uint32_t x, int r) {
    return (x << r) | (x >> (32 - r));
}

__device__ __forceinline__ void threefry2x32(uint32_t k0, uint32_t k1,
                                             uint32_t& x0, uint32_t& x1) {
    uint32_t ks0 = k0, ks1 = k1, ks2 = k0 ^ k1 ^ 0x1BD11BDAu;
    x0 += ks0; x1 += ks1;
    x0 += x1; x1 = rotl32(x1, 13); x1 ^= x0;
    x0 += x1; x1 = rotl32(x1, 15); x1 ^= x0;
    x0 += x1; x1 = rotl32(x1, 26); x1 ^= x0;
    x0 += x1; x1 = rotl32(x1, 6);  x1 ^= x0;
    x0 += ks1; x1 += ks2 + 1u;
    x0 += x1; x1 = rotl32(x1, 17); x1 ^= x0;
    x0 += x1; x1 = rotl32(x1, 29); x1 ^= x0;
    x0 += x1; x1 = rotl32(x1, 16); x1 ^= x0;
    x0 += x1; x1 = rotl32(x1, 24); x1 ^= x0;
    x0 += ks2; x1 += ks0 + 2u;
    x0 += x1; x1 = rotl32(x1, 13); x1 ^= x0;
    x0 += x1; x1 = rotl32(x1, 15); x1 ^= x0;
    x0 += x1; x1 = rotl32(x1, 26); x1 ^= x0;
    x0 += x1; x1 = rotl32(x1, 6);  x1 ^= x0;
    x0 += ks0; x1 += ks1 + 3u;
    x0 += x1; x1 = rotl32(x1, 17); x1 ^= x0;
    x0 += x1; x1 = rotl32(x1, 29); x1 ^= x0;
    x0 += x1; x1 = rotl32(x1, 16); x1 ^= x0;
    x0 += x1; x1 = rotl32(x1, 24); x1 ^= x0;
    x0 += ks1; x1 += ks2 + 4u;
    x0 += x1; x1 = rotl32(x1, 13); x1 ^= x0;
    x0 += x1; x1 = rotl32(x1, 15); x1 ^= x0;
    x0 += x1; x1 = rotl32(x1, 26); x1 ^= x0;
    x0 += x1; x1 = rotl32(x1, 6);  x1 ^= x0;
    x0 += ks2; x1 += ks0 + 5u;
}

// ---------- fused node precompute + dist table (f32) ----------
__global__ __launch_bounds__(128) void k_node(
    const float* __restrict__ x, const float* __restrict__ aerial,
    const float* __restrict__ Wlin, const float* __restrict__ blin,
    const float* __restrict__ Wq, const float* __restrict__ bq,
    const float* __restrict__ Wv, const float* __restrict__ bv,
    const float* __restrict__ dtab,
    float* __restrict__ xl32, float* __restrict__ q32, float* __restrict__ v32,
    float* __restrict__ dq32) {
    __shared__ float xinT[H_DIM][8];   // [k][m]
    __shared__ float xsT[H_DIM][8];
    __shared__ float aerT[A_DIM][8];
    const int j = threadIdx.x;

    if (blockIdx.x >= NODE_BLKS) {
        // ---- dist path (verbatim former k_dist) ----
        const int n0 = (blockIdx.x - NODE_BLKS) * 8;
#pragma unroll
        for (int m = 0; m < 8; ++m) xinT[j][m] = dtab[(size_t)(n0 + m) * H_DIM + j];
        __syncthreads();
        float acc[8];
#pragma unroll
        for (int m = 0; m < 8; ++m) acc[m] = 0.0f;
        for (int k = 0; k < H_DIM; ++k) {
            float w = Wq[(size_t)(H_DIM + A_DIM + k) * H_DIM + j];
            const float4* xp = (const float4*)&xinT[k][0];
            float4 a0 = xp[0], a1 = xp[1];
            acc[0] = fmaf(a0.x, w, acc[0]); acc[1] = fmaf(a0.y, w, acc[1]);
            acc[2] = fmaf(a0.z, w, acc[2]); acc[3] = fmaf(a0.w, w, acc[3]);
            acc[4] = fmaf(a1.x, w, acc[4]); acc[5] = fmaf(a1.y, w, acc[5]);
            acc[6] = fmaf(a1.z, w, acc[6]); acc[7] = fmaf(a1.w, w, acc[7]);
        }
#pragma unroll
        for (int m = 0; m < 8; ++m) dq32[(size_t)(n0 + m) * H_DIM + j] = acc[m];
        return;
    }

    const int n0 = blockIdx.x * 8;
#pragma unroll
    for (int m = 0; m < 8; ++m) xinT[j][m] = x[(size_t)(n0 + m) * H_DIM + j];
#pragma unroll
    for (int m = 0; m < 8; ++m)
#pragma unroll
        for (int c = 0; c < 4; ++c)
            aerT[c * H_DIM + j][m] = aerial[(size_t)(n0 + m) * A_DIM + c * H_DIM + j];
    __syncthreads();
    // xl = x @ Wlin + blin
    float acc[8];
    {
        float bj = blin[j];
#pragma unroll
        for (int m = 0; m < 8; ++m) acc[m] = bj;
        for (int k = 0; k < H_DIM; ++k) {
            float w = Wlin[k * H_DIM + j];
            const float4* xp = (const float4*)&xinT[k][0];
            float4 a0 = xp[0], a1 = xp[1];
            acc[0] = fmaf(a0.x, w, acc[0]); acc[1] = fmaf(a0.y, w, acc[1]);
            acc[2] = fmaf(a0.z, w, acc[2]); acc[3] = fmaf(a0.w, w, acc[3]);
            acc[4] = fmaf(a1.x, w, acc[4]); acc[5] = fmaf(a1.y, w, acc[5]);
            acc[6] = fmaf(a1.z, w, acc[6]); acc[7] = fmaf(a1.w, w, acc[7]);
        }
    }
#pragma unroll
    for (int m = 0; m < 8; ++m) {
        xsT[j][m] = acc[m];
        xl32[(size_t)(n0 + m) * H_DIM + j] = acc[m];
    }
    __syncthreads();
    // v_node = xl @ Wv + bv
    {
        float bj = bv[j];
        float av[8];
#pragma unroll
        for (int m = 0; m < 8; ++m) av[m] = bj;
        for (int k = 0; k < H_DIM; ++k) {
            float w = Wv[k * H_DIM + j];
            const float4* xp = (const float4*)&xsT[k][0];
            float4 a0 = xp[0], a1 = xp[1];
            av[0] = fmaf(a0.x, w, av[0]); av[1] = fmaf(a0.y, w, av[1]);
            av[2] = fmaf(a0.z, w, av[2]); av[3] = fmaf(a0.w, w, av[3]);
            av[4] = fmaf(a1.x, w, av[4]); av[5] = fmaf(a1.y, w, av[5]);
            av[6] = fmaf(a1.z, w, av[6]); av[7] = fmaf(a1.w, w, av[7]);
        }
#pragma unroll
        for (int m = 0; m < 8; ++m) v32[(size_t)(n0 + m) * H_DIM + j] = av[m];
    }
    // q_node = xl @ Wq[0:128] + aerial @ Wq[128:640] + bq
    {
        float bj = bq[j];
        float aq[8];
#pragma unroll
        for (int m = 0; m < 8; ++m) aq[m] = bj;
        for (int k = 0; k < H_DIM; ++k) {
            float w = Wq[k * H_DIM + j];
            const float4* xp = (const float4*)&xsT[k][0];
            float4 a0 = xp[0], a1 = xp[1];
            aq[0] = fmaf(a0.x, w, aq[0]); aq[1] = fmaf(a0.y, w, aq[1]);
            aq[2] = fmaf(a0.z, w, aq[2]); aq[3] = fmaf(a0.w, w, aq[3]);
            aq[4] = fmaf(a1.x, w, aq[4]); aq[5] = fmaf(a1.y, w, aq[5]);
            aq[6] = fmaf(a1.z, w, aq[6]); aq[7] = fmaf(a1.w, w, aq[7]);
        }
        for (int k = 0; k < A_DIM; ++k) {
            float w = Wq[(size_t)(H_DIM + k) * H_DIM + j];
            const float4* xp = (const float4*)&aerT[k][0];
            float4 a0 = xp[0], a1 = xp[1];
            aq[0] = fmaf(a0.x, w, aq[0]); aq[1] = fmaf(a0.y, w, aq[1]);
            aq[2] = fmaf(a0.z, w, aq[2]); aq[3] = fmaf(a0.w, w, aq[3]);
            aq[4] = fmaf(a1.x, w, aq[4]); aq[5] = fmaf(a1.y, w, aq[5]);
            aq[6] = fmaf(a1.z, w, aq[6]); aq[7] = fmaf(a1.w, w, aq[7]);
        }
#pragma unroll
        for (int m = 0; m < 8; ++m) q32[(size_t)(n0 + m) * H_DIM + j] = aq[m];
    }
}

// ---------- per-edge score: 32-lane group handles 4 edges (measured best) ----------
// Histogram on the TOP 20 BITS of the monotone sort key (key>>44):
// fine enough (11 mantissa bits) that no bin is hot -> no atomic stall.
// T is still the exact rank-K_SEL order statistic of the unique keys.
__global__ __launch_bounds__(256) void k_score(
    const int* __restrict__ ei, const int* __restrict__ dist,
    const float* __restrict__ q32, const float* __restrict__ v32,
    const float* __restrict__ dq32,
    unsigned long long* __restrict__ keys,
    unsigned* __restrict__ hist1) {
    const int g = threadIdx.x >> 5, lane = threadIdx.x & 31;
    const int e0 = blockIdx.x * 32 + g * 4;

    const int s0 = ei[e0 + 0], s1 = ei[e0 + 1], s2 = ei[e0 + 2], s3 = ei[e0 + 3];
    const int t0 = ei[E_EDGES + e0 + 0], t1 = ei[E_EDGES + e0 + 1];
    const int t2 = ei[E_EDGES + e0 + 2], t3 = ei[E_EDGES + e0 + 3];
    const int d0 = dist[e0 + 0] / 50, d1 = dist[e0 + 1] / 50;
    const int d2 = dist[e0 + 2] / 50, d3 = dist[e0 + 3] / 50;

    float4 q0 = ((const float4*)(q32 + (size_t)s0 * H_DIM))[lane];
    float4 q1 = ((const float4*)(q32 + (size_t)s1 * H_DIM))[lane];
    float4 q2 = ((const float4*)(q32 + (size_t)s2 * H_DIM))[lane];
    float4 q3 = ((const float4*)(q32 + (size_t)s3 * H_DIM))[lane];
    float4 v0 = ((const float4*)(v32 + (size_t)t0 * H_DIM))[lane];
    float4 v1 = ((const float4*)(v32 + (size_t)t1 * H_DIM))[lane];
    float4 v2 = ((const float4*)(v32 + (size_t)t2 * H_DIM))[lane];
    float4 v3 = ((const float4*)(v32 + (size_t)t3 * H_DIM))[lane];
    float4 w0 = ((const float4*)(dq32 + (size_t)d0 * H_DIM))[lane];
    float4 w1 = ((const float4*)(dq32 + (size_t)d1 * H_DIM))[lane];
    float4 w2 = ((const float4*)(dq32 + (size_t)d2 * H_DIM))[lane];
    float4 w3 = ((const float4*)(dq32 + (size_t)d3 * H_DIM))[lane];

    float ax, ay, az, aw;
    ax = q0.x + w0.x - v0.x; ay = q0.y + w0.y - v0.y;
    az = q0.z + w0.z - v0.z; aw = q0.w + w0.w - v0.w;
    float ss0 = fmaf(ax, ax, fmaf(ay, ay, fmaf(az, az, aw * aw)));
    ax = q1.x + w1.x - v1.x; ay = q1.y + w1.y - v1.y;
    az = q1.z + w1.z - v1.z; aw = q1.w + w1.w - v1.w;
    float ss1 = fmaf(ax, ax, fmaf(ay, ay, fmaf(az, az, aw * aw)));
    ax = q2.x + w2.x - v2.x; ay = q2.y + w2.y - v2.y;
    az = q2.z + w2.z - v2.z; aw = q2.w + w2.w - v2.w;
    float ss2 = fmaf(ax, ax, fmaf(ay, ay, fmaf(az, az, aw * aw)));
    ax = q3.x + w3.x - v3.x; ay = q3.y + w3.y - v3.y;
    az = q3.z + w3.z - v3.z; aw = q3.w + w3.w - v3.w;
    float ss3 = fmaf(ax, ax, fmaf(ay, ay, fmaf(az, az, aw * aw)));

#pragma unroll
    for (int o = 16; o > 0; o >>= 1) {
        ss0 += __shfl_xor(ss0, o, 64);
        ss1 += __shfl_xor(ss1, o, 64);
        ss2 += __shfl_xor(ss2, o, 64);
        ss3 += __shfl_xor(ss3, o, 64);
    }
    if (lane < 4) {
        float ssv = (lane == 0) ? ss0 : (lane == 1) ? ss1 : (lane == 2) ? ss2 : ss3;
        const int e = e0 + lane;
        // inline JAX threefry: counter=(0,e), key=(0,42), bits = out0^out1
        uint32_t x0r = 0u, x1r = (uint32_t)e;
        threefry2x32(0u, 42u, x0r, x1r);
        uint32_t bits = x0r ^ x1r;
        float uu = __uint_as_float((bits >> 9) | 0x3f800000u) - 1.0f;
        float nrm = sqrtf(ssv);
        float a = -logf(uu + 1e-20f);
        float gm = -logf(a + 1e-20f);
        float score = gm - nrm;
        int ib = __float_as_int(score);
        unsigned m32 = (ib < 0) ? ~(unsigned)ib : ((unsigned)ib | 0x80000000u);
        // unique key: score-ordered high bits, lower edge index wins ties
        unsigned long long key =
            ((unsigned long long)m32 << 32) | (unsigned)(0xFFFFFFFFu - (unsigned)e);
        keys[e] = key;
        atomicAdd(&hist1[(unsigned)(key >> 44)], 1u);
    }
}

// grid-parallel coarse sums: block b sums hist[b*1024 .. b*1024+1023]
// (R12's single-block k_scan serially read the whole 4MB table -> 186us;
// this distributes the same read across 1024 blocks)
__global__ __launch_bounds__(256) void k_coarse(const unsigned* __restrict__ hist,
                                                unsigned* __restrict__ coarse) {
    __shared__ unsigned red[256];
    const int t = threadIdx.x;
    const uint4 v = *(const uint4*)(hist + (size_t)blockIdx.x * SCAN_PER + t * 4);
    red[t] = v.x + v.y + v.z + v.w;
    __syncthreads();
    for (int o = 128; o > 0; o >>= 1) {
        if (t < o) red[t] += red[t + o];
        __syncthreads();
    }
    if (t == 0) coarse[blockIdx.x] = red[0];
}

// descending scan: coarse[1024] locates the chunk, then the chunk's
// 1024 bins locate the exact bin holding rank K_SEL
__global__ __launch_bounds__(1024) void k_scan(const unsigned* __restrict__ hist,
                                               const unsigned* __restrict__ coarse,
                                               SelState* st) {
    __shared__ unsigned csum[NCOARSE];
    __shared__ unsigned binv[SCAN_PER];
    __shared__ int selc;
    __shared__ unsigned cumbase;
    const int t = threadIdx.x;
    csum[t] = coarse[t];
    __syncthreads();
    if (t == 0) {
        unsigned cum = 0; int c = NCOARSE - 1;
        for (; c >= 0; --c) {
            if (cum + csum[c] >= K_SEL) break;
            cum += csum[c];
        }
        selc = c; cumbase = cum;
    }
    __syncthreads();
    binv[t] = hist[(size_t)selc * SCAN_PER + t];
    __syncthreads();
    if (t == 0) {
        unsigned cum = cumbase; int b = -1;
        for (int i = SCAN_PER - 1; i >= 0; --i) {
            if (cum + binv[i] >= K_SEL) { b = selc * SCAN_PER + i; break; }
            cum += binv[i];
        }
        st->b1 = b; st->cum1 = cum; st->r1 = K_SEL - cum;
    }
}

__global__ __launch_bounds__(256) void k_collect(
    const unsigned long long* __restrict__ keys,
    const SelState* __restrict__ st, unsigned long long* __restrict__ cand,
    unsigned* __restrict__ cnt) {
    int e = blockIdx.x * 256 + threadIdx.x;
    if (e >= E_EDGES) return;
    unsigned long long k = keys[e];
    if ((int)(unsigned)(k >> 44) != st->b1) return;
    unsigned p = atomicAdd(cnt, 1u);
    if (p < CAND_MAX) cand[p] = k;
}

// T = r1-th largest key among candidates (keys are unique)
__global__ __launch_bounds__(1024) void k_thresh(
    const unsigned long long* __restrict__ cand, const unsigned* __restrict__ cnt,
    SelState* st) {
    int c = (int)min(*cnt, (unsigned)CAND_MAX);
    unsigned r = st->r1;
    for (int i = threadIdx.x; i < c; i += 1024) {
        unsigned long long ki = cand[i];
        unsigned g = 0;
        for (int j = 0; j < c; ++j) g += (cand[j] > ki);
        if (g == r - 1) st->T = ki;
    }
}

// wave per edge: key >= T selects; scatter xl[src] into msg[tgt] + deg
__global__ __launch_bounds__(256) void k_scatter(
    const int* __restrict__ ei, const unsigned long long* __restrict__ keys,
    const SelState* __restrict__ st, const float* __restrict__ xl32,
    float* __restrict__ msg, float* __restrict__ deg) {
    const int wid = threadIdx.x >> 6, lane = threadIdx.x & 63;
    const int e = blockIdx.x * 4 + wid;
    if (keys[e] >= st->T) {
        int sidx = ei[e], tidx = ei[E_EDGES + e];
        const float* xp = xl32 + (size_t)sidx * H_DIM;
        float* mp = msg + (size_t)tidx * H_DIM;
        const int h = lane * 2;
        atomicAdd(&mp[h], xp[h]);
        atomicAdd(&mp[h + 1], xp[h + 1]);
        if (lane == 0) atomicAdd(&deg[tidx], 1.0f);
    }
}

// out = (msg/max(deg,1)) @ Wl + bl + xl @ Wr
__global__ __launch_bounds__(128) void k_out(
    const float* __restrict__ msg, const float* __restrict__ deg,
    const float* __restrict__ xl32, const float* __restrict__ Wl,
    const float* __restrict__ bl, const float* __restrict__ Wr,
    float* __restrict__ out) {
    __shared__ float axT[H_DIM][8];
    __shared__ float xxT[H_DIM][8];
    const int j = threadIdx.x;
    const int n0 = blockIdx.x * 8;
#pragma unroll
    for (int m = 0; m < 8; ++m) {
        float d = fmaxf(deg[n0 + m], 1.0f);
        axT[j][m] = msg[(size_t)(n0 + m) * H_DIM + j] / d;
        xxT[j][m] = xl32[(size_t)(n0 + m) * H_DIM + j];
    }
    __syncthreads();
    float acc[8];
    float bj = bl[j];
#pragma unroll
    for (int m = 0; m < 8; ++m) acc[m] = bj;
    for (int k = 0; k < H_DIM; ++k) {
        float wl = Wl[k * H_DIM + j];
        float wr = Wr[k * H_DIM + j];
        const float4* ap = (const float4*)&axT[k][0];
        const float4* xp = (const float4*)&xxT[k][0];
        float4 a0 = ap[0], a1 = ap[1];
        float4 x0 = xp[0], x1 = xp[1];
        acc[0] = fmaf(a0.x, wl, fmaf(x0.x, wr, acc[0]));
        acc[1] = fmaf(a0.y, wl, fmaf(x0.y, wr, acc[1]));
        acc[2] = fmaf(a0.z, wl, fmaf(x0.z, wr, acc[2]));
        acc[3] = fmaf(a0.w, wl, fmaf(x0.w, wr, acc[3]));
        acc[4] = fmaf(a1.x, wl, fmaf(x1.x, wr, acc[4]));
        acc[5] = fmaf(a1.y, wl, fmaf(x1.y, wr, acc[5]));
        acc[6] = fmaf(a1.z, wl, fmaf(x1.z, wr, acc[6]));
        acc[7] = fmaf(a1.w, wl, fmaf(x1.w, wr, acc[7]));
    }
#pragma unroll
    for (int m = 0; m < 8; ++m) out[(size_t)(n0 + m) * H_DIM + j] = acc[m];
}

extern "C" void kernel_launch(void* const* d_in, const int* in_sizes, int n_in,
                              void* d_out, int out_size, void* d_ws, size_t ws_size,
                              hipStream_t stream) {
    const float* x      = (const float*)d_in[0];
    const int*   ei     = (const int*)d_in[1];
    const int*   dist   = (const int*)d_in[2];
    const float* aerial = (const float*)d_in[3];
    const float* Wlin   = (const float*)d_in[4];
    const float* blin   = (const float*)d_in[5];
    const float* Wq     = (const float*)d_in[6];
    const float* bq     = (const float*)d_in[7];
    const float* Wv     = (const float*)d_in[8];
    const float* bv     = (const float*)d_in[9];
    const float* dtab   = (const float*)d_in[10];
    const float* Wl     = (const float*)d_in[11];
    const float* bl     = (const float*)d_in[12];
    const float* Wr     = (const float*)d_in[13];
    float* out = (float*)d_out;

    char* ws = (char*)d_ws;
    size_t off = 0;
    auto alloc = [&](size_t bytes) -> void* {
        void* p = ws + off;
        off += (bytes + 255) & ~(size_t)255;
        return p;
    };
    float* q32  = (float*)alloc((size_t)N_NODES * H_DIM * 4);
    float* v32  = (float*)alloc((size_t)N_NODES * H_DIM * 4);
    float* dq32 = (float*)alloc((size_t)NEMB_N * H_DIM * 4);
    unsigned long long* keys = (unsigned long long*)alloc((size_t)E_EDGES * 8);
    float* xl32 = (float*)alloc((size_t)N_NODES * H_DIM * 4);
    unsigned* coarse = (unsigned*)alloc((size_t)NCOARSE * 4);
    unsigned long long* cand = (unsigned long long*)alloc((size_t)CAND_MAX * 8);
    char* zbase = ws + off;
    float* msg  = (float*)alloc((size_t)N_NODES * H_DIM * 4);
    float* deg  = (float*)alloc((size_t)N_NODES * 4);
    unsigned* hist1 = (unsigned*)alloc((size_t)NBK * 4);
    unsigned* counters = (unsigned*)alloc(256);   // [0]=candCount
    SelState* st = (SelState*)alloc(256);
    size_t zlen = (size_t)((ws + off) - zbase);

    hipMemsetAsync(zbase, 0, zlen, stream);

    k_node<<<NODE_BLKS + DIST_BLKS, 128, 0, stream>>>(
        x, aerial, Wlin, blin, Wq, bq, Wv, bv, dtab, xl32, q32, v32, dq32);
    k_score<<<E_EDGES / 32, 256, 0, stream>>>(ei, dist, q32, v32, dq32,
                                              keys, hist1);
    k_coarse<<<NCOARSE, 256, 0, stream>>>(hist1, coarse);
    k_scan<<<1, 1024, 0, stream>>>(hist1, coarse, st);
    k_collect<<<(E_EDGES + 255) / 256, 256, 0, stream>>>(keys, st, cand, &counters[0]);
    k_thresh<<<1, 1024, 0, stream>>>(cand, &counters[0], st);
    k_scatter<<<E_EDGES / 4, 256, 0, stream>>>(ei, keys, st, xl32, msg, deg);
    k_out<<<N_NODES / 8, 128, 0, stream>>>(msg, deg, xl32, Wl, bl, Wr, out);
}